// Round 1
// baseline (1924.918 us; speedup 1.0000x reference)
//
#include <hip/hip_runtime.h>
#include <math.h>

// Problem constants
#define D_DIM 768          // feature dim / FFT length
#define NF    385          // rfft bins = D/2+1
#define NSP   772          // 2*NF padded to multiple of 4 (16B-aligned row stride)
#define BATCH 4
#define SEQ   4096
#define MROWS (BATCH*SEQ)  // 16384

#define PI_D 3.14159265358979323846

// ---------------------------------------------------------------------------
// Build forward DFT table Ftab[e][2f],[2f+1] = cos, -sin (e,f < 768,385)
// and inverse table G[2f][n], [2f+1][n] (irfft as matmul, 1/768 + 2x weights)
// Pad columns/rows beyond 770 are zeroed.
// ---------------------------------------------------------------------------
__global__ void build_tables(float* __restrict__ Ftab, float* __restrict__ G) {
    int idx = blockIdx.x * blockDim.x + threadIdx.x;
    int stride = gridDim.x * blockDim.x;
    const int totalF = D_DIM * NSP;   // Ftab: [768][772]
    for (int i = idx; i < totalF; i += stride) {
        int e = i / NSP, c = i % NSP;
        float val = 0.0f;
        if (c < 2 * NF) {
            int f = c >> 1;
            int m = (e * f) % D_DIM;
            double ang = (2.0 * PI_D / (double)D_DIM) * (double)m;
            val = (c & 1) ? (float)(-sin(ang)) : (float)cos(ang);
        }
        Ftab[i] = val;
    }
    const int totalG = NSP * D_DIM;   // G: [772][768]
    for (int i = idx; i < totalG; i += stride) {
        int r = i / D_DIM, n = i % D_DIM;
        double val = 0.0;
        if (r < 2 * NF) {
            int f = r >> 1;
            double w = (f == 0 || f == NF - 1) ? 1.0 : 2.0;
            int m = (f * n) % D_DIM;
            double ang = (2.0 * PI_D / (double)D_DIM) * (double)m;
            if (r & 1) {
                // imaginary-part coefficient; DC & Nyquist imag ignored by irfft
                val = (f == 0 || f == NF - 1) ? 0.0 : (-w * sin(ang) / (double)D_DIM);
            } else {
                val = w * cos(ang) / (double)D_DIM;
            }
        }
        G[i] = (float)val;
    }
}

// ---------------------------------------------------------------------------
// 768x768 transpose (W is [e][d] row-major; we need W^T = [d][e])
// ---------------------------------------------------------------------------
__global__ void transpose768(const float* __restrict__ A, float* __restrict__ AT) {
    __shared__ float tile[32][33];
    int bx = blockIdx.x, by = blockIdx.y;
    int x = bx * 32 + threadIdx.x;
    #pragma unroll
    for (int j = 0; j < 32; j += 8) {
        int y = by * 32 + threadIdx.y + j;
        tile[threadIdx.y + j][threadIdx.x] = A[y * D_DIM + x];
    }
    __syncthreads();
    int xo = by * 32 + threadIdx.x;
    #pragma unroll
    for (int j = 0; j < 32; j += 8) {
        int yo = bx * 32 + threadIdx.y + j;
        AT[yo * D_DIM + xo] = tile[threadIdx.x][threadIdx.y + j];
    }
}

// ---------------------------------------------------------------------------
// fp32 GEMM: C[M,N] = A[M,K] @ B[K,N]  (row-major, bounds-checked)
// optional epilogue: C = addend + gain[0] * (A@B)
// 64x64 block tile, 16x16 threads, 4x4 per thread, K-tile 16.
// ---------------------------------------------------------------------------
__global__ __launch_bounds__(256) void gemm_f32(
    const float* __restrict__ A, const float* __restrict__ B, float* __restrict__ C,
    int M, int N, int K,
    const float* __restrict__ addend, const float* __restrict__ gain)
{
    __shared__ float As[16][68];   // [kk][m], padded row (68*4B, 16B aligned)
    __shared__ float Bs[16][64];   // [kk][n]

    const int tid = threadIdx.x;
    const int tx = tid & 15, ty = tid >> 4;
    const int m0 = blockIdx.y * 64, n0 = blockIdx.x * 64;

    float acc[4][4] = {};

    const int ktiles = (K + 15) >> 4;
    for (int kt = 0; kt < ktiles; ++kt) {
        const int k0 = kt * 16;
        // --- stage A tile: 64 rows x 16 cols as 256 float4s ---
        {
            int r  = tid >> 2;          // 0..63
            int c4 = (tid & 3) * 4;     // 0,4,8,12
            int gm = m0 + r, gk = k0 + c4;
            float4 av = make_float4(0.f, 0.f, 0.f, 0.f);
            if (gm < M) {
                if (gk + 3 < K) {
                    av = *(const float4*)(A + (size_t)gm * K + gk);
                } else {
                    float t0=0.f,t1=0.f,t2=0.f,t3=0.f;
                    if (gk+0 < K) t0 = A[(size_t)gm*K + gk+0];
                    if (gk+1 < K) t1 = A[(size_t)gm*K + gk+1];
                    if (gk+2 < K) t2 = A[(size_t)gm*K + gk+2];
                    if (gk+3 < K) t3 = A[(size_t)gm*K + gk+3];
                    av = make_float4(t0,t1,t2,t3);
                }
            }
            As[c4+0][r] = av.x; As[c4+1][r] = av.y;
            As[c4+2][r] = av.z; As[c4+3][r] = av.w;
        }
        // --- stage B tile: 16 rows x 64 cols as 256 float4s ---
        {
            int r  = tid >> 4;          // 0..15
            int c4 = (tid & 15) * 4;    // 0..60
            int gk = k0 + r, gn = n0 + c4;
            float4 bv = make_float4(0.f, 0.f, 0.f, 0.f);
            if (gk < K) {
                if (gn + 3 < N) {
                    bv = *(const float4*)(B + (size_t)gk * N + gn);
                } else {
                    float t0=0.f,t1=0.f,t2=0.f,t3=0.f;
                    if (gn+0 < N) t0 = B[(size_t)gk*N + gn+0];
                    if (gn+1 < N) t1 = B[(size_t)gk*N + gn+1];
                    if (gn+2 < N) t2 = B[(size_t)gk*N + gn+2];
                    if (gn+3 < N) t3 = B[(size_t)gk*N + gn+3];
                    bv = make_float4(t0,t1,t2,t3);
                }
            }
            *(float4*)&Bs[r][c4] = bv;
        }
        __syncthreads();
        #pragma unroll
        for (int kk = 0; kk < 16; ++kk) {
            float4 a = *(const float4*)&As[kk][ty * 4];
            float4 b = *(const float4*)&Bs[kk][tx * 4];
            float ar[4] = {a.x, a.y, a.z, a.w};
            float br[4] = {b.x, b.y, b.z, b.w};
            #pragma unroll
            for (int i = 0; i < 4; ++i)
                #pragma unroll
                for (int j = 0; j < 4; ++j)
                    acc[i][j] += ar[i] * br[j];
        }
        __syncthreads();
    }

    const float g = gain ? gain[0] : 1.0f;
    #pragma unroll
    for (int i = 0; i < 4; ++i) {
        int gm = m0 + ty * 4 + i;
        if (gm >= M) continue;
        #pragma unroll
        for (int j = 0; j < 4; ++j) {
            int gn = n0 + tx * 4 + j;
            if (gn >= N) continue;
            size_t off = (size_t)gm * N + gn;
            float v = acc[i][j];
            if (addend) v = addend[off] + g * v;
            C[off] = v;
        }
    }
}

// ---------------------------------------------------------------------------
// Causal complex scan per (b,f): mem += kf*vf; O = mem*conj(qf).
// Writes O in place over specK. 1540 independent chains.
// ---------------------------------------------------------------------------
__global__ void scan_kernel(float* __restrict__ specK,
                            const float* __restrict__ specV,
                            const float* __restrict__ specQ)
{
    int idx = blockIdx.x * blockDim.x + threadIdx.x;
    if (idx >= BATCH * NF) return;
    int b = idx / NF, f = idx % NF;
    size_t base = (size_t)b * SEQ * NSP + 2 * f;
    float mr = 0.f, mi = 0.f;
    for (int s = 0; s < SEQ; ++s) {
        size_t off = base + (size_t)s * NSP;
        float2 kf = *(const float2*)(specK + off);
        float2 vf = *(const float2*)(specV + off);
        float2 qf = *(const float2*)(specQ + off);
        mr += kf.x * vf.x - kf.y * vf.y;
        mi += kf.x * vf.y + kf.y * vf.x;
        float orr = mr * qf.x + mi * qf.y;
        float oi  = mi * qf.x - mr * qf.y;
        *(float2*)(specK + off) = make_float2(orr, oi);
    }
}

// ---------------------------------------------------------------------------
// kernel_launch
// Workspace layout (floats), total ~166 MB:
//   Ftab [768*772] | G [772*768] | WT [768*768] | Ck,Cv,Cq [768*772 each]
//   specK, specV, specQ [16384*772 each]
// ---------------------------------------------------------------------------
extern "C" void kernel_launch(void* const* d_in, const int* in_sizes, int n_in,
                              void* d_out, int out_size, void* d_ws, size_t ws_size,
                              hipStream_t stream) {
    const float* x    = (const float*)d_in[0];
    const float* Wk   = (const float*)d_in[1];
    const float* Wv   = (const float*)d_in[2];
    const float* Wq   = (const float*)d_in[3];
    const float* gain = (const float*)d_in[4];
    float* out = (float*)d_out;

    float* ws    = (float*)d_ws;
    float* Ftab  = ws;
    float* G     = Ftab  + (size_t)D_DIM * NSP;
    float* WT    = G     + (size_t)NSP * D_DIM;
    float* Ck    = WT    + (size_t)D_DIM * D_DIM;
    float* Cv    = Ck    + (size_t)D_DIM * NSP;
    float* Cq    = Cv    + (size_t)D_DIM * NSP;
    float* specK = Cq    + (size_t)D_DIM * NSP;
    float* specV = specK + (size_t)MROWS * NSP;
    float* specQ = specV + (size_t)MROWS * NSP;

    // 1. DFT tables
    build_tables<<<1024, 256, 0, stream>>>(Ftab, G);

    // 2. Combined projection+DFT matrices: C_i = W_i^T @ Ftab  [768 x 772]
    dim3 tgrid(24, 24), tblk(32, 8);
    dim3 cgrid((NSP + 63) / 64, (D_DIM + 63) / 64);   // 13 x 12
    transpose768<<<tgrid, tblk, 0, stream>>>(Wk, WT);
    gemm_f32<<<cgrid, 256, 0, stream>>>(WT, Ftab, Ck, D_DIM, NSP, D_DIM, nullptr, nullptr);
    transpose768<<<tgrid, tblk, 0, stream>>>(Wv, WT);
    gemm_f32<<<cgrid, 256, 0, stream>>>(WT, Ftab, Cv, D_DIM, NSP, D_DIM, nullptr, nullptr);
    transpose768<<<tgrid, tblk, 0, stream>>>(Wq, WT);
    gemm_f32<<<cgrid, 256, 0, stream>>>(WT, Ftab, Cq, D_DIM, NSP, D_DIM, nullptr, nullptr);

    // 3. Spectra: spec_i = X @ C_i   [16384 x 772]
    dim3 sgrid((NSP + 63) / 64, (MROWS + 63) / 64);   // 13 x 256
    gemm_f32<<<sgrid, 256, 0, stream>>>(x, Ck, specK, MROWS, NSP, D_DIM, nullptr, nullptr);
    gemm_f32<<<sgrid, 256, 0, stream>>>(x, Cv, specV, MROWS, NSP, D_DIM, nullptr, nullptr);
    gemm_f32<<<sgrid, 256, 0, stream>>>(x, Cq, specQ, MROWS, NSP, D_DIM, nullptr, nullptr);

    // 4. Causal cumulative binding + unbind (in place into specK)
    scan_kernel<<<(BATCH * NF + 255) / 256, 256, 0, stream>>>(specK, specV, specQ);

    // 5. irfft + residual: out = x + gain * (O @ G)   [16384 x 768]
    dim3 ogrid((D_DIM + 63) / 64, (MROWS + 63) / 64); // 12 x 256
    gemm_f32<<<ogrid, 256, 0, stream>>>(specK, G, out, MROWS, D_DIM, NSP, x, gain);
}

// Round 2
// 1415.514 us; speedup vs baseline: 1.3599x; 1.3599x over previous
//
#include <hip/hip_runtime.h>
#include <math.h>

// Problem constants
#define D_DIM 768          // feature dim / FFT length
#define NF    385          // rfft bins = D/2+1
#define NSP   772          // 2*NF padded to multiple of 4
#define BATCH 4
#define SEQ   4096
#define MROWS (BATCH*SEQ)  // 16384

#define PI_D 3.14159265358979323846

// ---------------------------------------------------------------------------
// Build transposed forward DFT table FtabT [NSP][768]:
//   FtabT[2f][e] = cos(2*pi*e*f/768), FtabT[2f+1][e] = -sin(...)
// and inverse table G [NSP][768]:
//   G[2f][n] = w*cos(...)/768, G[2f+1][n] = -w*sin(...)/768  (w=1 at DC/Nyq, else 2)
// One sincos per (f,e) pair serves all 4 outputs. Rows 770,771 zeroed.
// ---------------------------------------------------------------------------
__global__ void build_tables(float* __restrict__ FtabT, float* __restrict__ G) {
    int idx = blockIdx.x * blockDim.x + threadIdx.x;
    int stride = gridDim.x * blockDim.x;
    const int total = NF * D_DIM;
    for (int i = idx; i < total; i += stride) {
        int f = i / D_DIM, e = i % D_DIM;
        int m = (e * f) % D_DIM;
        double ang = (2.0 * PI_D / (double)D_DIM) * (double)m;
        double s, c;
        sincos(ang, &s, &c);
        size_t ro = (size_t)(2 * f) * D_DIM + e;
        FtabT[ro]         = (float)c;
        FtabT[ro + D_DIM] = (float)(-s);
        double w = (f == 0 || f == NF - 1) ? 1.0 : 2.0;
        G[ro]         = (float)(w * c / (double)D_DIM);
        G[ro + D_DIM] = (f == 0 || f == NF - 1) ? 0.0f
                                                : (float)(-w * s / (double)D_DIM);
    }
    // zero pad rows 770, 771 of both tables
    for (int i = idx; i < 2 * D_DIM; i += stride) {
        FtabT[(size_t)770 * D_DIM + i] = 0.0f;
        G[(size_t)770 * D_DIM + i] = 0.0f;
    }
}

// ---------------------------------------------------------------------------
// Shared fp32 GEMM body pieces: 64x64 tile, 256 thr, 4x4/thread, K-tile 16.
// Three variants differing only in operand staging:
//   gemm_nn : C[M,N] = A[M,K] @ B[K,N]            (A,B row-major)
//   gemm_nt : C[M,N] = A[M,K] @ Bt[N,K]^T          (B supplied transposed)
//   gemm_tn : C[M,N] = At[K,M]^T @ B[K,N] (+ epi)  (A supplied transposed)
// ---------------------------------------------------------------------------

#define GEMM_COMPUTE_LOOP()                                              \
    _Pragma("unroll")                                                    \
    for (int kk = 0; kk < 16; ++kk) {                                    \
        float4 a = *(const float4*)&As[kk][ty * 4];                      \
        float4 b = *(const float4*)&Bs[kk][tx * 4];                      \
        float ar[4] = {a.x, a.y, a.z, a.w};                              \
        float br[4] = {b.x, b.y, b.z, b.w};                              \
        _Pragma("unroll")                                                \
        for (int i = 0; i < 4; ++i)                                      \
            _Pragma("unroll")                                            \
            for (int j = 0; j < 4; ++j)                                  \
                acc[i][j] += ar[i] * br[j];                              \
    }

__global__ __launch_bounds__(256) void gemm_nn(
    const float* __restrict__ A, const float* __restrict__ B, float* __restrict__ C,
    int M, int N, int K)
{
    __shared__ float As[16][68];
    __shared__ float Bs[16][68];
    const int tid = threadIdx.x;
    const int tx = tid & 15, ty = tid >> 4;
    const int m0 = blockIdx.y * 64, n0 = blockIdx.x * 64;
    float acc[4][4] = {};
    const int ktiles = (K + 15) >> 4;
    for (int kt = 0; kt < ktiles; ++kt) {
        const int k0 = kt * 16;
        {   // A tile: 64 m-rows x 16 k-cols
            int r = tid >> 2, c4 = (tid & 3) * 4;
            int gm = m0 + r, gk = k0 + c4;
            float4 av = make_float4(0.f,0.f,0.f,0.f);
            if (gm < M && gk + 3 < K) av = *(const float4*)(A + (size_t)gm*K + gk);
            else if (gm < M) {
                float t[4] = {0,0,0,0};
                for (int u = 0; u < 4; ++u) if (gk+u < K) t[u] = A[(size_t)gm*K + gk+u];
                av = make_float4(t[0],t[1],t[2],t[3]);
            }
            As[c4+0][r]=av.x; As[c4+1][r]=av.y; As[c4+2][r]=av.z; As[c4+3][r]=av.w;
        }
        {   // B tile: 16 k-rows x 64 n-cols
            int r = tid >> 4, c4 = (tid & 15) * 4;
            int gk = k0 + r, gn = n0 + c4;
            float4 bv = make_float4(0.f,0.f,0.f,0.f);
            if (gk < K && gn + 3 < N) bv = *(const float4*)(B + (size_t)gk*N + gn);
            else if (gk < K) {
                float t[4] = {0,0,0,0};
                for (int u = 0; u < 4; ++u) if (gn+u < N) t[u] = B[(size_t)gk*N + gn+u];
                bv = make_float4(t[0],t[1],t[2],t[3]);
            }
            *(float4*)&Bs[r][c4] = bv;
        }
        __syncthreads();
        GEMM_COMPUTE_LOOP();
        __syncthreads();
    }
    #pragma unroll
    for (int i = 0; i < 4; ++i) {
        int gm = m0 + ty * 4 + i;
        if (gm >= M) continue;
        #pragma unroll
        for (int j = 0; j < 4; ++j) {
            int gn = n0 + tx * 4 + j;
            if (gn >= N) continue;
            C[(size_t)gm * N + gn] = acc[i][j];
        }
    }
}

// C[M,N] = A[M,K] @ Bt[N,K]^T  — used for specT = CT @ x^T (Bt = x, N=16384, K=768)
__global__ __launch_bounds__(256) void gemm_nt(
    const float* __restrict__ A, const float* __restrict__ Bt, float* __restrict__ C,
    int M, int N, int K)
{
    __shared__ float As[16][68];
    __shared__ float Bs[16][68];
    const int tid = threadIdx.x;
    const int tx = tid & 15, ty = tid >> 4;
    const int m0 = blockIdx.y * 64, n0 = blockIdx.x * 64;
    float acc[4][4] = {};
    const int ktiles = (K + 15) >> 4;   // K=768 exact here
    for (int kt = 0; kt < ktiles; ++kt) {
        const int k0 = kt * 16;
        {   // A tile (row-major, M guard)
            int r = tid >> 2, c4 = (tid & 3) * 4;
            int gm = m0 + r, gk = k0 + c4;
            float4 av = make_float4(0.f,0.f,0.f,0.f);
            if (gm < M) av = *(const float4*)(A + (size_t)gm*K + gk);
            As[c4+0][r]=av.x; As[c4+1][r]=av.y; As[c4+2][r]=av.z; As[c4+3][r]=av.w;
        }
        {   // B tile from Bt[n][k]: 64 n-rows x 16 k-cols (N,K exact multiples)
            int r = tid >> 2, c4 = (tid & 3) * 4;
            int gn = n0 + r, gk = k0 + c4;
            float4 bv = *(const float4*)(Bt + (size_t)gn*K + gk);
            Bs[c4+0][r]=bv.x; Bs[c4+1][r]=bv.y; Bs[c4+2][r]=bv.z; Bs[c4+3][r]=bv.w;
        }
        __syncthreads();
        GEMM_COMPUTE_LOOP();
        __syncthreads();
    }
    #pragma unroll
    for (int i = 0; i < 4; ++i) {
        int gm = m0 + ty * 4 + i;
        if (gm >= M) continue;
        #pragma unroll
        for (int j = 0; j < 4; ++j) {
            int gn = n0 + tx * 4 + j;
            C[(size_t)gm * N + gn] = acc[i][j];
        }
    }
}

// C[M,N] = At[K,M]^T @ B[K,N], epilogue C = addend + gain*acc
// used for out = OT^T @ G + x*gain (At = OT [772][16384], M=16384, N=768, K=772)
__global__ __launch_bounds__(256) void gemm_tn(
    const float* __restrict__ At, const float* __restrict__ B, float* __restrict__ C,
    int M, int N, int K,
    const float* __restrict__ addend, const float* __restrict__ gain)
{
    __shared__ float As[16][68];
    __shared__ float Bs[16][68];
    const int tid = threadIdx.x;
    const int tx = tid & 15, ty = tid >> 4;
    const int m0 = blockIdx.y * 64, n0 = blockIdx.x * 64;
    float acc[4][4] = {};
    const int ktiles = (K + 15) >> 4;
    for (int kt = 0; kt < ktiles; ++kt) {
        const int k0 = kt * 16;
        {   // A tile from At[k][m]: 16 k-rows x 64 m-cols (contiguous!)
            int r = tid >> 4, c4 = (tid & 15) * 4;
            int gk = k0 + r, gm = m0 + c4;
            float4 av = make_float4(0.f,0.f,0.f,0.f);
            if (gk < K) av = *(const float4*)(At + (size_t)gk*M + gm);
            *(float4*)&As[r][0] = av;   // placeholder avoided; real write below
            // note: need As[kk][m] layout — row-contiguous write:
            As[r][c4+0]=av.x; As[r][c4+1]=av.y; As[r][c4+2]=av.z; As[r][c4+3]=av.w;
        }
        {   // B tile: 16 k-rows x 64 n-cols (row-contiguous, K guard; N=768 exact)
            int r = tid >> 4, c4 = (tid & 15) * 4;
            int gk = k0 + r, gn = n0 + c4;
            float4 bv = make_float4(0.f,0.f,0.f,0.f);
            if (gk < K) bv = *(const float4*)(B + (size_t)gk*N + gn);
            *(float4*)&Bs[r][c4] = bv;
        }
        __syncthreads();
        // compute: acc[i][j] += As[kk][ty*4+i] * Bs[kk][tx*4+j]
        #pragma unroll
        for (int kk = 0; kk < 16; ++kk) {
            float4 a = *(const float4*)&As[kk][ty * 4];
            float4 b = *(const float4*)&Bs[kk][tx * 4];
            float ar[4] = {a.x, a.y, a.z, a.w};
            float br[4] = {b.x, b.y, b.z, b.w};
            #pragma unroll
            for (int i = 0; i < 4; ++i)
                #pragma unroll
                for (int j = 0; j < 4; ++j)
                    acc[i][j] += ar[i] * br[j];
        }
        __syncthreads();
    }
    const float g = gain[0];
    #pragma unroll
    for (int i = 0; i < 4; ++i) {
        int gm = m0 + ty * 4 + i;
        #pragma unroll
        for (int j = 0; j < 4; ++j) {
            int gn = n0 + tx * 4 + j;
            size_t off = (size_t)gm * N + gn;
            C[off] = addend[off] + g * acc[i][j];
        }
    }
}

// ---------------------------------------------------------------------------
// Parallel causal complex scan, transposed layout.
// specT_*: [NSP rows][MROWS cols]; chain (b,f): re at row 2f, im at row 2f+1,
// cols b*SEQ .. b*SEQ+4095 (contiguous). One 256-thread block per chain;
// thread t owns s = t*16..t*16+15. In-place output over specTK.
// ---------------------------------------------------------------------------
__global__ __launch_bounds__(256) void scan_blocks(
    float* __restrict__ specTK,
    const float* __restrict__ specTV,
    const float* __restrict__ specTQ)
{
    const int blk = blockIdx.x;           // 0 .. 4*385-1
    const int b = blk / NF, f = blk % NF;
    const int tid = threadIdx.x;
    const int lane = tid & 63, wid = tid >> 6;

    const size_t colbase = (size_t)b * SEQ;
    float* Kre = specTK + (size_t)(2*f)   * MROWS + colbase;
    float* Kim = specTK + (size_t)(2*f+1) * MROWS + colbase;
    const float* Vre = specTV + (size_t)(2*f)   * MROWS + colbase;
    const float* Vim = specTV + (size_t)(2*f+1) * MROWS + colbase;
    const float* Qre = specTQ + (size_t)(2*f)   * MROWS + colbase;
    const float* Qim = specTQ + (size_t)(2*f+1) * MROWS + colbase;

    const int s0 = tid * 16;
    float pr[16], pi[16];
    // products p = kf * vf (complex), then local inclusive cumsum
    #pragma unroll
    for (int c = 0; c < 4; ++c) {
        float4 kr = *(const float4*)(Kre + s0 + c*4);
        float4 ki = *(const float4*)(Kim + s0 + c*4);
        float4 vr = *(const float4*)(Vre + s0 + c*4);
        float4 vi = *(const float4*)(Vim + s0 + c*4);
        const float krx[4] = {kr.x,kr.y,kr.z,kr.w};
        const float kix[4] = {ki.x,ki.y,ki.z,ki.w};
        const float vrx[4] = {vr.x,vr.y,vr.z,vr.w};
        const float vix[4] = {vi.x,vi.y,vi.z,vi.w};
        #pragma unroll
        for (int u = 0; u < 4; ++u) {
            pr[c*4+u] = krx[u]*vrx[u] - kix[u]*vix[u];
            pi[c*4+u] = krx[u]*vix[u] + kix[u]*vrx[u];
        }
    }
    #pragma unroll
    for (int j = 1; j < 16; ++j) { pr[j] += pr[j-1]; pi[j] += pi[j-1]; }
    const float totr = pr[15], toti = pi[15];

    // wave-level inclusive scan of thread totals
    float sr = totr, si = toti;
    #pragma unroll
    for (int d = 1; d < 64; d <<= 1) {
        float ur = __shfl_up(sr, d, 64);
        float ui = __shfl_up(si, d, 64);
        if (lane >= d) { sr += ur; si += ui; }
    }
    __shared__ float wsr[4], wsi[4];
    if (lane == 63) { wsr[wid] = sr; wsi[wid] = si; }
    __syncthreads();
    float baser = 0.f, basei = 0.f;
    #pragma unroll
    for (int w = 0; w < 3; ++w) {
        if (w < wid) { baser += wsr[w]; basei += wsi[w]; }
    }
    const float exr = baser + sr - totr;   // exclusive prefix for this thread
    const float exi = basei + si - toti;

    // mem = ex + local cumsum; O = mem * conj(qf); write in place
    #pragma unroll
    for (int c = 0; c < 4; ++c) {
        float4 qr = *(const float4*)(Qre + s0 + c*4);
        float4 qi = *(const float4*)(Qim + s0 + c*4);
        const float qrx[4] = {qr.x,qr.y,qr.z,qr.w};
        const float qix[4] = {qi.x,qi.y,qi.z,qi.w};
        float4 outr, outi;
        float orx[4], oix[4];
        #pragma unroll
        for (int u = 0; u < 4; ++u) {
            float mr = exr + pr[c*4+u];
            float mi = exi + pi[c*4+u];
            orx[u] = mr*qrx[u] + mi*qix[u];
            oix[u] = mi*qrx[u] - mr*qix[u];
        }
        outr = make_float4(orx[0],orx[1],orx[2],orx[3]);
        outi = make_float4(oix[0],oix[1],oix[2],oix[3]);
        *(float4*)(Kre + s0 + c*4) = outr;
        *(float4*)(Kim + s0 + c*4) = outi;
    }
}

// ---------------------------------------------------------------------------
// kernel_launch
// Workspace (floats):
//   FtabT [772*768] | G [772*768] | CTk,CTv,CTq [772*768 each]
//   specTK, specTV, specTQ [772*16384 each]       total ≈ 163 MB
// ---------------------------------------------------------------------------
extern "C" void kernel_launch(void* const* d_in, const int* in_sizes, int n_in,
                              void* d_out, int out_size, void* d_ws, size_t ws_size,
                              hipStream_t stream) {
    const float* x    = (const float*)d_in[0];
    const float* Wk   = (const float*)d_in[1];
    const float* Wv   = (const float*)d_in[2];
    const float* Wq   = (const float*)d_in[3];
    const float* gain = (const float*)d_in[4];
    float* out = (float*)d_out;

    float* ws     = (float*)d_ws;
    float* FtabT  = ws;
    float* G      = FtabT  + (size_t)NSP * D_DIM;
    float* CTk    = G      + (size_t)NSP * D_DIM;
    float* CTv    = CTk    + (size_t)NSP * D_DIM;
    float* CTq    = CTv    + (size_t)NSP * D_DIM;
    float* specTK = CTq    + (size_t)NSP * D_DIM;
    float* specTV = specTK + (size_t)NSP * MROWS;
    float* specTQ = specTV + (size_t)NSP * MROWS;

    // 1. DFT tables (transposed forward + inverse)
    build_tables<<<1024, 256, 0, stream>>>(FtabT, G);

    // 2. CT_i = FtabT @ W_i  [772 x 768], K=768
    dim3 cgrid(D_DIM / 64, (NSP + 63) / 64);          // 12 x 13
    gemm_nn<<<cgrid, 256, 0, stream>>>(FtabT, Wk, CTk, NSP, D_DIM, D_DIM);
    gemm_nn<<<cgrid, 256, 0, stream>>>(FtabT, Wv, CTv, NSP, D_DIM, D_DIM);
    gemm_nn<<<cgrid, 256, 0, stream>>>(FtabT, Wq, CTq, NSP, D_DIM, D_DIM);

    // 3. specT_i = CT_i @ x^T  [772 x 16384], K=768
    dim3 sgrid(MROWS / 64, (NSP + 63) / 64);          // 256 x 13
    gemm_nt<<<sgrid, 256, 0, stream>>>(CTk, x, specTK, NSP, MROWS, D_DIM);
    gemm_nt<<<sgrid, 256, 0, stream>>>(CTv, x, specTV, NSP, MROWS, D_DIM);
    gemm_nt<<<sgrid, 256, 0, stream>>>(CTq, x, specTQ, NSP, MROWS, D_DIM);

    // 4. causal binding scan + unbind (in place into specTK), contiguous chains
    scan_blocks<<<BATCH * NF, 256, 0, stream>>>(specTK, specTV, specTQ);

    // 5. out = x + gain * (OT^T @ G)  [16384 x 768], K=772
    dim3 ogrid(D_DIM / 64, MROWS / 64);               // 12 x 256
    gemm_tn<<<ogrid, 256, 0, stream>>>(specTK, G, out, MROWS, D_DIM, NSP, x, gain);
}

// Round 3
// 312.910 us; speedup vs baseline: 6.1517x; 4.5237x over previous
//
#include <hip/hip_runtime.h>
#include <math.h>

#define D_DIM 768
#define NF    385
#define NSP   772          // 2*NF pad-to-4
#define BATCH 4
#define SEQ   4096
#define MROWS 16384
#define KP5   800          // stage-5 K padded to multiple of 32 (and 16B rows)
#define SPECZ ((size_t)NSP * MROWS)

typedef __bf16 bf16x8 __attribute__((ext_vector_type(8)));
typedef float  f32x4  __attribute__((ext_vector_type(4)));

// async global->LDS, 16B per lane; LDS dest is wave-uniform base + lane*16
__device__ __forceinline__ void gl2lds16(const __bf16* g, __bf16* l) {
    __builtin_amdgcn_global_load_lds(
        (const __attribute__((address_space(1))) void*)g,
        (__attribute__((address_space(3))) void*)l, 16, 0, 0);
}

// ---------------------------------------------------------------------------
// DFT tables, bf16: FtabT [772][768]: rows 2f=cos, 2f+1=-sin; pad rows 770,771=0.
// GT [768][800]: GT[n][2f]=w*cos/768, GT[n][2f+1]=-w*sin/768 (w=1 DC/Nyq else 2,
// imag coeff 0 at DC/Nyq); pad cols 770..799 = 0.
// ---------------------------------------------------------------------------
__global__ void build_tables(__bf16* __restrict__ FtabT, __bf16* __restrict__ GT) {
    int idx = blockIdx.x * blockDim.x + threadIdx.x;
    int stride = gridDim.x * blockDim.x;
    const float w0 = 6.28318530717958647692f / (float)D_DIM;
    for (int i = idx; i < NF * D_DIM; i += stride) {
        int f = i / D_DIM, e = i - f * D_DIM;
        int m = (e * f) % D_DIM;             // exact angle reduction
        float s, c;
        __sincosf(w0 * (float)m, &s, &c);
        FtabT[(size_t)(2*f)   * D_DIM + e] = (__bf16)c;
        FtabT[(size_t)(2*f+1) * D_DIM + e] = (__bf16)(-s);
        bool dcny = (f == 0) || (f == NF - 1);
        float w = dcny ? (1.0f / D_DIM) : (2.0f / D_DIM);
        GT[(size_t)e * KP5 + 2*f]     = (__bf16)(w * c);
        GT[(size_t)e * KP5 + 2*f + 1] = dcny ? (__bf16)0.0f : (__bf16)(-w * s);
    }
    for (int i = idx; i < 2 * D_DIM; i += stride)
        FtabT[(size_t)770 * D_DIM + i] = (__bf16)0.0f;
    for (int i = idx; i < D_DIM * (KP5 - 2 * NF); i += stride) {
        int r = i / (KP5 - 2 * NF), c = 2 * NF + (i % (KP5 - 2 * NF));
        GT[(size_t)r * KP5 + c] = (__bf16)0.0f;
    }
}

// x fp32 [16384][768] -> bf16 flat
__global__ void cvt_x(const float* __restrict__ xin, __bf16* __restrict__ xout) {
    int idx = blockIdx.x * blockDim.x + threadIdx.x;
    int stride = gridDim.x * blockDim.x;
    const int total8 = MROWS * D_DIM / 8;
    const float4* x4 = (const float4*)xin;
    for (int i = idx; i < total8; i += stride) {
        float4 a = x4[2*i], b = x4[2*i+1];
        bf16x8 o;
        o[0]=(__bf16)a.x; o[1]=(__bf16)a.y; o[2]=(__bf16)a.z; o[3]=(__bf16)a.w;
        o[4]=(__bf16)b.x; o[5]=(__bf16)b.y; o[6]=(__bf16)b.z; o[7]=(__bf16)b.w;
        *((bf16x8*)xout + i) = o;
    }
}

// W_z [768][768] fp32 -> WT[z*768+d][e] bf16  (stacked N x K for NT GEMM)
__global__ void transposeW(const float* __restrict__ W0, const float* __restrict__ W1,
                           const float* __restrict__ W2, __bf16* __restrict__ WT) {
    const float* W = blockIdx.z == 0 ? W0 : (blockIdx.z == 1 ? W1 : W2);
    __shared__ float tile[32][33];
    const int tx = threadIdx.x, ty = threadIdx.y;
    const int e0 = blockIdx.x * 32, d0 = blockIdx.y * 32;
    #pragma unroll
    for (int j = 0; j < 4; ++j)
        tile[ty + j*8][tx] = W[(size_t)(e0 + ty + j*8) * D_DIM + d0 + tx];
    __syncthreads();
    __bf16* WTz = WT + (size_t)blockIdx.z * D_DIM * D_DIM;
    #pragma unroll
    for (int j = 0; j < 4; ++j)
        WTz[(size_t)(d0 + ty + j*8) * D_DIM + e0 + tx] = (__bf16)tile[tx][ty + j*8];
}

// OT bf16 [772][16384] -> O bf16 [16384][800] (cols 772..799 zero)
__global__ void transposeO(const __bf16* __restrict__ OT, __bf16* __restrict__ O) {
    __shared__ __bf16 tile[32][34];
    const int tx = threadIdx.x, ty = threadIdx.y;
    const int m0 = blockIdx.x * 32, c0 = blockIdx.y * 32;
    #pragma unroll
    for (int j = 0; j < 4; ++j) {
        int c = c0 + ty + j*8;
        __bf16 v = (__bf16)0.0f;
        if (c < NSP) v = OT[(size_t)c * MROWS + m0 + tx];
        tile[ty + j*8][tx] = v;
    }
    __syncthreads();
    #pragma unroll
    for (int j = 0; j < 4; ++j)
        O[(size_t)(m0 + ty + j*8) * KP5 + c0 + tx] = tile[tx][ty + j*8];
}

// ---------------------------------------------------------------------------
// bf16 NT MFMA GEMM (m97 recipe): C[M,N] = A[M,K] @ Bt[N,K]^T
// 128x128 tile, BK=32, 4 waves (2x2 of 64x64), 16x16x32 MFMA.
// A rows clamped to M-1 for staging (C-write guarded). N,K exact multiples.
// c_bf16: write bf16; else fp32 with optional epilogue addend + gain*acc.
// grid.z batches A (strideAz elements) and C (strideCz elements).
// ---------------------------------------------------------------------------
__global__ __launch_bounds__(256) void mfma_nt(
    const __bf16* __restrict__ A, const __bf16* __restrict__ B, void* __restrict__ Cv,
    int M, int N, int K, int lda, int ldb, int ldc,
    long strideAz, long strideCz, int c_bf16,
    const float* __restrict__ addend, const float* __restrict__ gain)
{
    __shared__ __bf16 As[128 * 32];
    __shared__ __bf16 Bs[128 * 32];
    const int tid  = threadIdx.x;
    const int wave = tid >> 6, lane = tid & 63;
    const int lrow = lane & 15, lquad = lane >> 4;
    const int wm = wave >> 1, wn = wave & 1;
    const int m0 = blockIdx.y * 128, n0 = blockIdx.x * 128;
    const __bf16* Az = A + (size_t)blockIdx.z * strideAz;

    const int sr = tid >> 2;          // 0..63
    const int sc = (tid & 3) * 8;     // 0,8,16,24
    int ra0 = m0 + sr;      if (ra0 > M - 1) ra0 = M - 1;
    int ra1 = m0 + sr + 64; if (ra1 > M - 1) ra1 = M - 1;
    const int rb0 = n0 + sr, rb1 = n0 + sr + 64;
    __bf16* ldsA0 = As + wave * 512;
    __bf16* ldsA1 = As + 2048 + wave * 512;
    __bf16* ldsB0 = Bs + wave * 512;
    __bf16* ldsB1 = Bs + 2048 + wave * 512;

    f32x4 acc[4][4];
    #pragma unroll
    for (int i = 0; i < 4; ++i)
        #pragma unroll
        for (int j = 0; j < 4; ++j)
            acc[i][j] = (f32x4){0.f, 0.f, 0.f, 0.f};

    for (int k0 = 0; k0 < K; k0 += 32) {
        gl2lds16(Az + (size_t)ra0 * lda + k0 + sc, ldsA0);
        gl2lds16(Az + (size_t)ra1 * lda + k0 + sc, ldsA1);
        gl2lds16(B  + (size_t)rb0 * ldb + k0 + sc, ldsB0);
        gl2lds16(B  + (size_t)rb1 * ldb + k0 + sc, ldsB1);
        __syncthreads();
        bf16x8 af[4], bfr[4];
        #pragma unroll
        for (int i = 0; i < 4; ++i) {
            af[i]  = *(const bf16x8*)&As[(wm*64 + i*16 + lrow) * 32 + lquad*8];
            bfr[i] = *(const bf16x8*)&Bs[(wn*64 + i*16 + lrow) * 32 + lquad*8];
        }
        #pragma unroll
        for (int i = 0; i < 4; ++i)
            #pragma unroll
            for (int j = 0; j < 4; ++j)
                acc[i][j] = __builtin_amdgcn_mfma_f32_16x16x32_bf16(
                    af[i], bfr[j], acc[i][j], 0, 0, 0);
        __syncthreads();
    }

    // C/D layout (verified m89): col = lane&15, row = (lane>>4)*4 + reg
    const int colb = n0 + wn * 64 + lrow;
    const int rowb = m0 + wm * 64 + lquad * 4;
    if (c_bf16) {
        __bf16* C = (__bf16*)Cv + (size_t)blockIdx.z * strideCz;
        #pragma unroll
        for (int i = 0; i < 4; ++i)
            #pragma unroll
            for (int j = 0; j < 4; ++j) {
                const int col = colb + j * 16;
                #pragma unroll
                for (int r = 0; r < 4; ++r) {
                    const int mm = rowb + i * 16 + r;
                    if (mm < M) C[(size_t)mm * ldc + col] = (__bf16)acc[i][j][r];
                }
            }
    } else if (addend) {
        float* C = (float*)Cv;
        const float g = gain[0];
        #pragma unroll
        for (int i = 0; i < 4; ++i)
            #pragma unroll
            for (int j = 0; j < 4; ++j) {
                const int col = colb + j * 16;
                #pragma unroll
                for (int r = 0; r < 4; ++r) {
                    const int mm = rowb + i * 16 + r;
                    if (mm < M) {
                        const size_t off = (size_t)mm * ldc + col;
                        C[off] = addend[off] + g * acc[i][j][r];
                    }
                }
            }
    } else {
        float* C = (float*)Cv + (size_t)blockIdx.z * strideCz;
        #pragma unroll
        for (int i = 0; i < 4; ++i)
            #pragma unroll
            for (int j = 0; j < 4; ++j) {
                const int col = colb + j * 16;
                #pragma unroll
                for (int r = 0; r < 4; ++r) {
                    const int mm = rowb + i * 16 + r;
                    if (mm < M) C[(size_t)mm * ldc + col] = acc[i][j][r];
                }
            }
    }
}

// ---------------------------------------------------------------------------
// Causal complex scan over bf16 spectra (transposed layout), in place over K.
// One block per (b,f) chain; thread t owns 16 consecutive s.
// ---------------------------------------------------------------------------
__global__ __launch_bounds__(256) void scan_blocks(__bf16* __restrict__ spec) {
    const int blk = blockIdx.x;
    const int b = blk / NF, f = blk % NF;
    const int tid = threadIdx.x;
    const int lane = tid & 63, wid = tid >> 6;
    const size_t colbase = (size_t)b * SEQ;
    __bf16* Kre = spec + (size_t)(2*f) * MROWS + colbase;
    __bf16* Kim = Kre + MROWS;
    const __bf16* Vre = Kre + SPECZ;
    const __bf16* Vim = Vre + MROWS;
    const __bf16* Qre = Kre + 2 * SPECZ;
    const __bf16* Qim = Qre + MROWS;
    const int s0 = tid * 16;

    bf16x8 kr0 = *(const bf16x8*)(Kre + s0), kr1 = *(const bf16x8*)(Kre + s0 + 8);
    bf16x8 ki0 = *(const bf16x8*)(Kim + s0), ki1 = *(const bf16x8*)(Kim + s0 + 8);
    bf16x8 vr0 = *(const bf16x8*)(Vre + s0), vr1 = *(const bf16x8*)(Vre + s0 + 8);
    bf16x8 vi0 = *(const bf16x8*)(Vim + s0), vi1 = *(const bf16x8*)(Vim + s0 + 8);

    float pr[16], pi[16];
    #pragma unroll
    for (int u = 0; u < 8; ++u) {
        float a = (float)kr0[u], bq = (float)ki0[u], c = (float)vr0[u], d = (float)vi0[u];
        pr[u] = a * c - bq * d;
        pi[u] = a * d + bq * c;
        float a1 = (float)kr1[u], b1 = (float)ki1[u], c1 = (float)vr1[u], d1 = (float)vi1[u];
        pr[8+u] = a1 * c1 - b1 * d1;
        pi[8+u] = a1 * d1 + b1 * c1;
    }
    #pragma unroll
    for (int j = 1; j < 16; ++j) { pr[j] += pr[j-1]; pi[j] += pi[j-1]; }
    const float totr = pr[15], toti = pi[15];

    float sr = totr, si = toti;
    #pragma unroll
    for (int d = 1; d < 64; d <<= 1) {
        float ur = __shfl_up(sr, d, 64);
        float ui = __shfl_up(si, d, 64);
        if (lane >= d) { sr += ur; si += ui; }
    }
    __shared__ float wsr[4], wsi[4];
    if (lane == 63) { wsr[wid] = sr; wsi[wid] = si; }
    __syncthreads();
    float baser = 0.f, basei = 0.f;
    #pragma unroll
    for (int w = 0; w < 3; ++w)
        if (w < wid) { baser += wsr[w]; basei += wsi[w]; }
    const float exr = baser + sr - totr;
    const float exi = basei + si - toti;

    bf16x8 qr0 = *(const bf16x8*)(Qre + s0), qr1 = *(const bf16x8*)(Qre + s0 + 8);
    bf16x8 qi0 = *(const bf16x8*)(Qim + s0), qi1 = *(const bf16x8*)(Qim + s0 + 8);
    bf16x8 outr0, outr1, outi0, outi1;
    #pragma unroll
    for (int u = 0; u < 8; ++u) {
        float mr = exr + pr[u],   mi = exi + pi[u];
        float qr = (float)qr0[u], qi = (float)qi0[u];
        outr0[u] = (__bf16)(mr * qr + mi * qi);
        outi0[u] = (__bf16)(mi * qr - mr * qi);
        float mr1 = exr + pr[8+u], mi1 = exi + pi[8+u];
        float qr_ = (float)qr1[u], qi_ = (float)qi1[u];
        outr1[u] = (__bf16)(mr1 * qr_ + mi1 * qi_);
        outi1[u] = (__bf16)(mi1 * qr_ - mr1 * qi_);
    }
    *(bf16x8*)(Kre + s0)     = outr0;
    *(bf16x8*)(Kre + s0 + 8) = outr1;
    *(bf16x8*)(Kim + s0)     = outi0;
    *(bf16x8*)(Kim + s0 + 8) = outi1;
}

// ---------------------------------------------------------------------------
// Workspace (bf16 elements): FtabT[772*768] | GT[768*800] | WT[2304*768]
//  | x16[16384*768] | CT[772*2304] | spec[3*772*16384]; O overlays specV/Q.
// Total ~110.6 MB.
// ---------------------------------------------------------------------------
extern "C" void kernel_launch(void* const* d_in, const int* in_sizes, int n_in,
                              void* d_out, int out_size, void* d_ws, size_t ws_size,
                              hipStream_t stream) {
    const float* x    = (const float*)d_in[0];
    const float* Wk   = (const float*)d_in[1];
    const float* Wv   = (const float*)d_in[2];
    const float* Wq   = (const float*)d_in[3];
    const float* gain = (const float*)d_in[4];
    float* out = (float*)d_out;

    __bf16* FtabT = (__bf16*)d_ws;
    __bf16* GT    = FtabT + (size_t)NSP * D_DIM;
    __bf16* WT    = GT    + (size_t)D_DIM * KP5;
    __bf16* x16   = WT    + (size_t)3 * D_DIM * D_DIM;
    __bf16* CT    = x16   + (size_t)MROWS * D_DIM;
    __bf16* spec  = CT    + (size_t)NSP * 3 * D_DIM;
    __bf16* O     = spec  + SPECZ;   // over specV/specQ (free after scan)

    build_tables<<<1184, 256, 0, stream>>>(FtabT, GT);
    cvt_x<<<3072, 256, 0, stream>>>(x, x16);
    transposeW<<<dim3(24, 24, 3), dim3(32, 8), 0, stream>>>(Wk, Wv, Wq, WT);

    // stage 2: CT[772][2304] = FtabT @ WT^T   (one dispatch, all 3 W)
    mfma_nt<<<dim3(18, 7, 1), 256, 0, stream>>>(
        FtabT, WT, CT, NSP, 3 * D_DIM, D_DIM,
        D_DIM, D_DIM, 3 * D_DIM, 0, 0, 1, nullptr, nullptr);

    // stage 3: spec_z[772][16384] = CT_z @ x16^T   (z = k,v,q)
    mfma_nt<<<dim3(128, 7, 3), 256, 0, stream>>>(
        CT, x16, spec, NSP, MROWS, D_DIM,
        3 * D_DIM, D_DIM, MROWS, (long)D_DIM, (long)SPECZ, 1, nullptr, nullptr);

    // stage 4: causal binding scan + unbind (in place over specK)
    scan_blocks<<<BATCH * NF, 256, 0, stream>>>(spec);

    // OT -> O bf16 [16384][800] (zero-padded cols)
    transposeO<<<dim3(512, 25), dim3(32, 8), 0, stream>>>(spec, O);

    // stage 5: out[16384][768] = x + gain * (O @ GT^T)
    mfma_nt<<<dim3(6, 128, 1), 256, 0, stream>>>(
        O, GT, out, MROWS, D_DIM, KP5,
        KP5, KP5, D_DIM, 0, 0, 0, x, gain);
}

// Round 4
// 308.151 us; speedup vs baseline: 6.2467x; 1.0154x over previous
//
#include <hip/hip_runtime.h>
#include <math.h>

#define D_DIM 768
#define NF    385
#define NSP   772          // 2*NF pad-to-4
#define BATCH 4
#define SEQ   4096
#define MROWS 16384
#define KP5   800          // stage-5 K padded to multiple of 32 (and 16B rows)
#define SPECZ ((size_t)NSP * MROWS)

typedef __bf16 bf16x8 __attribute__((ext_vector_type(8)));
typedef float  f32x4  __attribute__((ext_vector_type(4)));

// async global->LDS, 16B per lane; LDS dest is wave-uniform base + lane*16
__device__ __forceinline__ void gl2lds16(const __bf16* g, __bf16* l) {
    __builtin_amdgcn_global_load_lds(
        (const __attribute__((address_space(1))) void*)g,
        (__attribute__((address_space(3))) void*)l, 16, 0, 0);
}

// ---------------------------------------------------------------------------
// DFT tables, bf16: FtabT [772][768]: rows 2f=cos, 2f+1=-sin; pad rows 770,771=0.
// GT [768][800]: GT[n][2f]=w*cos/768, GT[n][2f+1]=-w*sin/768 (w=1 DC/Nyq else 2,
// imag coeff 0 at DC/Nyq); pad cols 770..799 = 0.
// ---------------------------------------------------------------------------
__global__ void build_tables(__bf16* __restrict__ FtabT, __bf16* __restrict__ GT) {
    int idx = blockIdx.x * blockDim.x + threadIdx.x;
    int stride = gridDim.x * blockDim.x;
    const float w0 = 6.28318530717958647692f / (float)D_DIM;
    for (int i = idx; i < NF * D_DIM; i += stride) {
        int f = i / D_DIM, e = i - f * D_DIM;
        int m = (e * f) % D_DIM;             // exact angle reduction
        float s, c;
        __sincosf(w0 * (float)m, &s, &c);
        FtabT[(size_t)(2*f)   * D_DIM + e] = (__bf16)c;
        FtabT[(size_t)(2*f+1) * D_DIM + e] = (__bf16)(-s);
        bool dcny = (f == 0) || (f == NF - 1);
        float w = dcny ? (1.0f / D_DIM) : (2.0f / D_DIM);
        GT[(size_t)e * KP5 + 2*f]     = (__bf16)(w * c);
        GT[(size_t)e * KP5 + 2*f + 1] = dcny ? (__bf16)0.0f : (__bf16)(-w * s);
    }
    for (int i = idx; i < 2 * D_DIM; i += stride)
        FtabT[(size_t)770 * D_DIM + i] = (__bf16)0.0f;
    for (int i = idx; i < D_DIM * (KP5 - 2 * NF); i += stride) {
        int r = i / (KP5 - 2 * NF), c = 2 * NF + (i % (KP5 - 2 * NF));
        GT[(size_t)r * KP5 + c] = (__bf16)0.0f;
    }
}

// x fp32 [16384][768] -> bf16 flat
__global__ void cvt_x(const float* __restrict__ xin, __bf16* __restrict__ xout) {
    int idx = blockIdx.x * blockDim.x + threadIdx.x;
    int stride = gridDim.x * blockDim.x;
    const int total8 = MROWS * D_DIM / 8;
    const float4* x4 = (const float4*)xin;
    for (int i = idx; i < total8; i += stride) {
        float4 a = x4[2*i], b = x4[2*i+1];
        bf16x8 o;
        o[0]=(__bf16)a.x; o[1]=(__bf16)a.y; o[2]=(__bf16)a.z; o[3]=(__bf16)a.w;
        o[4]=(__bf16)b.x; o[5]=(__bf16)b.y; o[6]=(__bf16)b.z; o[7]=(__bf16)b.w;
        *((bf16x8*)xout + i) = o;
    }
}

// W_z [768][768] fp32 -> WT[z*768+d][e] bf16  (stacked N x K for NT GEMM)
__global__ void transposeW(const float* __restrict__ W0, const float* __restrict__ W1,
                           const float* __restrict__ W2, __bf16* __restrict__ WT) {
    const float* W = blockIdx.z == 0 ? W0 : (blockIdx.z == 1 ? W1 : W2);
    __shared__ float tile[32][33];
    const int tx = threadIdx.x, ty = threadIdx.y;
    const int e0 = blockIdx.x * 32, d0 = blockIdx.y * 32;
    #pragma unroll
    for (int j = 0; j < 4; ++j)
        tile[ty + j*8][tx] = W[(size_t)(e0 + ty + j*8) * D_DIM + d0 + tx];
    __syncthreads();
    __bf16* WTz = WT + (size_t)blockIdx.z * D_DIM * D_DIM;
    #pragma unroll
    for (int j = 0; j < 4; ++j)
        WTz[(size_t)(d0 + ty + j*8) * D_DIM + e0 + tx] = (__bf16)tile[tx][ty + j*8];
}

// OT bf16 [772][16384] -> O bf16 [16384][800] (cols 772..799 zero)
__global__ void transposeO(const __bf16* __restrict__ OT, __bf16* __restrict__ O) {
    __shared__ __bf16 tile[32][34];
    const int tx = threadIdx.x, ty = threadIdx.y;
    const int m0 = blockIdx.x * 32, c0 = blockIdx.y * 32;
    #pragma unroll
    for (int j = 0; j < 4; ++j) {
        int c = c0 + ty + j*8;
        __bf16 v = (__bf16)0.0f;
        if (c < NSP) v = OT[(size_t)c * MROWS + m0 + tx];
        tile[ty + j*8][tx] = v;
    }
    __syncthreads();
    #pragma unroll
    for (int j = 0; j < 4; ++j)
        O[(size_t)(m0 + ty + j*8) * KP5 + c0 + tx] = tile[tx][ty + j*8];
}

// ---------------------------------------------------------------------------
// bf16 NT MFMA GEMM: C[M,N] = A[M,K] @ Bt[N,K]^T
// 128x128 tile, BK=32, 4 waves (2x2 of 64x64), 16x16x32 MFMA.
// LDS K-block XOR swizzle (kills the 8-way ds_read_b128 bank conflict):
//   data (row r, col-block c4) lives at LDS col-block c4 ^ ((r>>1)&3).
//   Implemented on the global-fetch side because global_load_lds's LDS dest
//   is hard-wired to base + lane*16: lane fetches col-block
//   (tid&3) ^ ((tid>>3)&3); reader de-swizzles with lquad ^ ((lrow>>1)&3).
//   Resulting bank base = (lrow&1)*16 + (lquad^((lrow>>1)&3))*4: 8 groups x
//   2 lanes = 2-way aliasing = free (m136).
// ---------------------------------------------------------------------------
__global__ __launch_bounds__(256) void mfma_nt(
    const __bf16* __restrict__ A, const __bf16* __restrict__ B, void* __restrict__ Cv,
    int M, int N, int K, int lda, int ldb, int ldc,
    long strideAz, long strideCz, int c_bf16,
    const float* __restrict__ addend, const float* __restrict__ gain)
{
    __shared__ __bf16 As[128 * 32];
    __shared__ __bf16 Bs[128 * 32];
    const int tid  = threadIdx.x;
    const int wave = tid >> 6, lane = tid & 63;
    const int lrow = lane & 15, lquad = lane >> 4;
    const int wm = wave >> 1, wn = wave & 1;
    const int m0 = blockIdx.y * 128, n0 = blockIdx.x * 128;
    const __bf16* Az = A + (size_t)blockIdx.z * strideAz;

    const int sr = tid >> 2;                               // 0..63
    const int sc = (((tid & 3) ^ ((tid >> 3) & 3))) * 8;   // swizzled K-block
    int ra0 = m0 + sr;      if (ra0 > M - 1) ra0 = M - 1;
    int ra1 = m0 + sr + 64; if (ra1 > M - 1) ra1 = M - 1;
    const int rb0 = n0 + sr, rb1 = n0 + sr + 64;
    __bf16* ldsA0 = As + wave * 512;
    __bf16* ldsA1 = As + 2048 + wave * 512;
    __bf16* ldsB0 = Bs + wave * 512;
    __bf16* ldsB1 = Bs + 2048 + wave * 512;

    const int swz = (lrow >> 1) & 3;                       // reader de-swizzle
    const int fragcol = (lquad ^ swz) * 8;

    f32x4 acc[4][4];
    #pragma unroll
    for (int i = 0; i < 4; ++i)
        #pragma unroll
        for (int j = 0; j < 4; ++j)
            acc[i][j] = (f32x4){0.f, 0.f, 0.f, 0.f};

    for (int k0 = 0; k0 < K; k0 += 32) {
        gl2lds16(Az + (size_t)ra0 * lda + k0 + sc, ldsA0);
        gl2lds16(Az + (size_t)ra1 * lda + k0 + sc, ldsA1);
        gl2lds16(B  + (size_t)rb0 * ldb + k0 + sc, ldsB0);
        gl2lds16(B  + (size_t)rb1 * ldb + k0 + sc, ldsB1);
        __syncthreads();
        bf16x8 af[4], bfr[4];
        #pragma unroll
        for (int i = 0; i < 4; ++i) {
            af[i]  = *(const bf16x8*)&As[(wm*64 + i*16 + lrow) * 32 + fragcol];
            bfr[i] = *(const bf16x8*)&Bs[(wn*64 + i*16 + lrow) * 32 + fragcol];
        }
        #pragma unroll
        for (int i = 0; i < 4; ++i)
            #pragma unroll
            for (int j = 0; j < 4; ++j)
                acc[i][j] = __builtin_amdgcn_mfma_f32_16x16x32_bf16(
                    af[i], bfr[j], acc[i][j], 0, 0, 0);
        __syncthreads();
    }

    // C/D layout (verified m89): col = lane&15, row = (lane>>4)*4 + reg
    const int colb = n0 + wn * 64 + lrow;
    const int rowb = m0 + wm * 64 + lquad * 4;
    if (c_bf16) {
        __bf16* C = (__bf16*)Cv + (size_t)blockIdx.z * strideCz;
        #pragma unroll
        for (int i = 0; i < 4; ++i)
            #pragma unroll
            for (int j = 0; j < 4; ++j) {
                const int col = colb + j * 16;
                #pragma unroll
                for (int r = 0; r < 4; ++r) {
                    const int mm = rowb + i * 16 + r;
                    if (mm < M) C[(size_t)mm * ldc + col] = (__bf16)acc[i][j][r];
                }
            }
    } else if (addend) {
        float* C = (float*)Cv;
        const float g = gain[0];
        #pragma unroll
        for (int i = 0; i < 4; ++i)
            #pragma unroll
            for (int j = 0; j < 4; ++j) {
                const int col = colb + j * 16;
                #pragma unroll
                for (int r = 0; r < 4; ++r) {
                    const int mm = rowb + i * 16 + r;
                    if (mm < M) {
                        const size_t off = (size_t)mm * ldc + col;
                        C[off] = addend[off] + g * acc[i][j][r];
                    }
                }
            }
    } else {
        float* C = (float*)Cv + (size_t)blockIdx.z * strideCz;
        #pragma unroll
        for (int i = 0; i < 4; ++i)
            #pragma unroll
            for (int j = 0; j < 4; ++j) {
                const int col = colb + j * 16;
                #pragma unroll
                for (int r = 0; r < 4; ++r) {
                    const int mm = rowb + i * 16 + r;
                    if (mm < M) C[(size_t)mm * ldc + col] = acc[i][j][r];
                }
            }
    }
}

// ---------------------------------------------------------------------------
// Causal complex scan over bf16 spectra (transposed layout), in place over K.
// One block per (b,f) chain; thread t owns 16 consecutive s.
// ---------------------------------------------------------------------------
__global__ __launch_bounds__(256) void scan_blocks(__bf16* __restrict__ spec) {
    const int blk = blockIdx.x;
    const int b = blk / NF, f = blk % NF;
    const int tid = threadIdx.x;
    const int lane = tid & 63, wid = tid >> 6;
    const size_t colbase = (size_t)b * SEQ;
    __bf16* Kre = spec + (size_t)(2*f) * MROWS + colbase;
    __bf16* Kim = Kre + MROWS;
    const __bf16* Vre = Kre + SPECZ;
    const __bf16* Vim = Vre + MROWS;
    const __bf16* Qre = Kre + 2 * SPECZ;
    const __bf16* Qim = Qre + MROWS;
    const int s0 = tid * 16;

    bf16x8 kr0 = *(const bf16x8*)(Kre + s0), kr1 = *(const bf16x8*)(Kre + s0 + 8);
    bf16x8 ki0 = *(const bf16x8*)(Kim + s0), ki1 = *(const bf16x8*)(Kim + s0 + 8);
    bf16x8 vr0 = *(const bf16x8*)(Vre + s0), vr1 = *(const bf16x8*)(Vre + s0 + 8);
    bf16x8 vi0 = *(const bf16x8*)(Vim + s0), vi1 = *(const bf16x8*)(Vim + s0 + 8);

    float pr[16], pi[16];
    #pragma unroll
    for (int u = 0; u < 8; ++u) {
        float a = (float)kr0[u], bq = (float)ki0[u], c = (float)vr0[u], d = (float)vi0[u];
        pr[u] = a * c - bq * d;
        pi[u] = a * d + bq * c;
        float a1 = (float)kr1[u], b1 = (float)ki1[u], c1 = (float)vr1[u], d1 = (float)vi1[u];
        pr[8+u] = a1 * c1 - b1 * d1;
        pi[8+u] = a1 * d1 + b1 * c1;
    }
    #pragma unroll
    for (int j = 1; j < 16; ++j) { pr[j] += pr[j-1]; pi[j] += pi[j-1]; }
    const float totr = pr[15], toti = pi[15];

    float sr = totr, si = toti;
    #pragma unroll
    for (int d = 1; d < 64; d <<= 1) {
        float ur = __shfl_up(sr, d, 64);
        float ui = __shfl_up(si, d, 64);
        if (lane >= d) { sr += ur; si += ui; }
    }
    __shared__ float wsr[4], wsi[4];
    if (lane == 63) { wsr[wid] = sr; wsi[wid] = si; }
    __syncthreads();
    float baser = 0.f, basei = 0.f;
    #pragma unroll
    for (int w = 0; w < 3; ++w)
        if (w < wid) { baser += wsr[w]; basei += wsi[w]; }
    const float exr = baser + sr - totr;
    const float exi = basei + si - toti;

    bf16x8 qr0 = *(const bf16x8*)(Qre + s0), qr1 = *(const bf16x8*)(Qre + s0 + 8);
    bf16x8 qi0 = *(const bf16x8*)(Qim + s0), qi1 = *(const bf16x8*)(Qim + s0 + 8);
    bf16x8 outr0, outr1, outi0, outi1;
    #pragma unroll
    for (int u = 0; u < 8; ++u) {
        float mr = exr + pr[u],   mi = exi + pi[u];
        float qr = (float)qr0[u], qi = (float)qi0[u];
        outr0[u] = (__bf16)(mr * qr + mi * qi);
        outi0[u] = (__bf16)(mi * qr - mr * qi);
        float mr1 = exr + pr[8+u], mi1 = exi + pi[8+u];
        float qr_ = (float)qr1[u], qi_ = (float)qi1[u];
        outr1[u] = (__bf16)(mr1 * qr_ + mi1 * qi_);
        outi1[u] = (__bf16)(mi1 * qr_ - mr1 * qi_);
    }
    *(bf16x8*)(Kre + s0)     = outr0;
    *(bf16x8*)(Kre + s0 + 8) = outr1;
    *(bf16x8*)(Kim + s0)     = outi0;
    *(bf16x8*)(Kim + s0 + 8) = outi1;
}

// ---------------------------------------------------------------------------
// Workspace (bf16 elements): FtabT[772*768] | GT[768*800] | WT[2304*768]
//  | x16[16384*768] | CT[772*2304] | spec[3*772*16384]; O overlays specV/Q.
// Total ~110.6 MB.
// ---------------------------------------------------------------------------
extern "C" void kernel_launch(void* const* d_in, const int* in_sizes, int n_in,
                              void* d_out, int out_size, void* d_ws, size_t ws_size,
                              hipStream_t stream) {
    const float* x    = (const float*)d_in[0];
    const float* Wk   = (const float*)d_in[1];
    const float* Wv   = (const float*)d_in[2];
    const float* Wq   = (const float*)d_in[3];
    const float* gain = (const float*)d_in[4];
    float* out = (float*)d_out;

    __bf16* FtabT = (__bf16*)d_ws;
    __bf16* GT    = FtabT + (size_t)NSP * D_DIM;
    __bf16* WT    = GT    + (size_t)D_DIM * KP5;
    __bf16* x16   = WT    + (size_t)3 * D_DIM * D_DIM;
    __bf16* CT    = x16   + (size_t)MROWS * D_DIM;
    __bf16* spec  = CT    + (size_t)NSP * 3 * D_DIM;
    __bf16* O     = spec  + SPECZ;   // over specV/specQ (free after scan)

    build_tables<<<1184, 256, 0, stream>>>(FtabT, GT);
    cvt_x<<<3072, 256, 0, stream>>>(x, x16);
    transposeW<<<dim3(24, 24, 3), dim3(32, 8), 0, stream>>>(Wk, Wv, Wq, WT);

    // stage 2: CT[772][2304] = FtabT @ WT^T   (one dispatch, all 3 W)
    mfma_nt<<<dim3(18, 7, 1), 256, 0, stream>>>(
        FtabT, WT, CT, NSP, 3 * D_DIM, D_DIM,
        D_DIM, D_DIM, 3 * D_DIM, 0, 0, 1, nullptr, nullptr);

    // stage 3: spec_z[772][16384] = CT_z @ x16^T   (z = k,v,q)
    mfma_nt<<<dim3(128, 7, 3), 256, 0, stream>>>(
        CT, x16, spec, NSP, MROWS, D_DIM,
        3 * D_DIM, D_DIM, MROWS, (long)D_DIM, (long)SPECZ, 1, nullptr, nullptr);

    // stage 4: causal binding scan + unbind (in place over specK)
    scan_blocks<<<BATCH * NF, 256, 0, stream>>>(spec);

    // OT -> O bf16 [16384][800] (zero-padded cols)
    transposeO<<<dim3(512, 25), dim3(32, 8), 0, stream>>>(spec, O);

    // stage 5: out[16384][768] = x + gain * (O @ GT^T)
    mfma_nt<<<dim3(6, 128, 1), 256, 0, stream>>>(
        O, GT, out, MROWS, D_DIM, KP5,
        KP5, KP5, D_DIM, 0, 0, 0, x, gain);
}

// Round 5
// 305.703 us; speedup vs baseline: 6.2967x; 1.0080x over previous
//
#include <hip/hip_runtime.h>
#include <math.h>

#define D_DIM 768
#define NF    385
#define NSP   772          // 2*NF pad-to-4
#define BATCH 4
#define SEQ   4096
#define MROWS 16384
#define KP5   800          // stage-5 K padded to multiple of 32
#define SPECZ ((size_t)NSP * MROWS)

typedef __bf16 bf16x8 __attribute__((ext_vector_type(8)));
typedef float  f32x4  __attribute__((ext_vector_type(4)));

// async global->LDS, 16B per lane; LDS dest is wave-uniform base + lane*16
__device__ __forceinline__ void gl2lds16(const __bf16* g, __bf16* l) {
    __builtin_amdgcn_global_load_lds(
        (const __attribute__((address_space(1))) void*)g,
        (__attribute__((address_space(3))) void*)l, 16, 0, 0);
}

// ---------------------------------------------------------------------------
// Fused prologue (one dispatch, 3 independent jobs partitioned by blockIdx):
//  [0,1728): transposeW — W_z [768][768] fp32 -> WT[z][d][e] bf16
//  [1728,2240): build DFT tables FtabT [772][768] + GT [768][800]
//  [2240,3264): cvt_x — x fp32 [16384][768] -> bf16 flat
// ---------------------------------------------------------------------------
__global__ __launch_bounds__(256) void prologue(
    __bf16* __restrict__ FtabT, __bf16* __restrict__ GT,
    const float* __restrict__ W0, const float* __restrict__ W1,
    const float* __restrict__ W2, __bf16* __restrict__ WT,
    const float* __restrict__ x, __bf16* __restrict__ x16)
{
    const int bid = blockIdx.x;
    const int tid = threadIdx.x;
    if (bid < 1728) {
        // ---- transposeW ----
        __shared__ float tile[32][33];
        const int bz = bid / 576, rem = bid % 576;
        const int bx = rem % 24, by = rem / 24;
        const float* W = bz == 0 ? W0 : (bz == 1 ? W1 : W2);
        const int tx = tid & 31, ty = tid >> 5;
        const int e0 = bx * 32, d0 = by * 32;
        #pragma unroll
        for (int j = 0; j < 4; ++j)
            tile[ty + j*8][tx] = W[(size_t)(e0 + ty + j*8) * D_DIM + d0 + tx];
        __syncthreads();
        __bf16* WTz = WT + (size_t)bz * D_DIM * D_DIM;
        #pragma unroll
        for (int j = 0; j < 4; ++j)
            WTz[(size_t)(d0 + ty + j*8) * D_DIM + e0 + tx] = (__bf16)tile[tx][ty + j*8];
    } else if (bid < 2240) {
        // ---- build tables ----
        int idx = (bid - 1728) * 256 + tid;
        const int stride = 512 * 256;
        const float w0 = 6.28318530717958647692f / (float)D_DIM;
        for (int i = idx; i < NF * D_DIM; i += stride) {
            int f = i / D_DIM, e = i - f * D_DIM;
            int m = (e * f) % D_DIM;             // exact angle reduction
            float s, c;
            __sincosf(w0 * (float)m, &s, &c);
            FtabT[(size_t)(2*f)   * D_DIM + e] = (__bf16)c;
            FtabT[(size_t)(2*f+1) * D_DIM + e] = (__bf16)(-s);
            bool dcny = (f == 0) || (f == NF - 1);
            float w = dcny ? (1.0f / D_DIM) : (2.0f / D_DIM);
            GT[(size_t)e * KP5 + 2*f]     = (__bf16)(w * c);
            GT[(size_t)e * KP5 + 2*f + 1] = dcny ? (__bf16)0.0f : (__bf16)(-w * s);
        }
        for (int i = idx; i < 2 * D_DIM; i += stride)
            FtabT[(size_t)770 * D_DIM + i] = (__bf16)0.0f;
        for (int i = idx; i < D_DIM * (KP5 - 2 * NF); i += stride) {
            int r = i / (KP5 - 2 * NF), c = 2 * NF + (i % (KP5 - 2 * NF));
            GT[(size_t)r * KP5 + c] = (__bf16)0.0f;
        }
    } else {
        // ---- cvt_x ----
        int idx = (bid - 2240) * 256 + tid;
        const int stride = 1024 * 256;
        const int total8 = MROWS * D_DIM / 8;
        const float4* x4 = (const float4*)x;
        for (int i = idx; i < total8; i += stride) {
            float4 a = x4[2*i], b = x4[2*i+1];
            bf16x8 o;
            o[0]=(__bf16)a.x; o[1]=(__bf16)a.y; o[2]=(__bf16)a.z; o[3]=(__bf16)a.w;
            o[4]=(__bf16)b.x; o[5]=(__bf16)b.y; o[6]=(__bf16)b.z; o[7]=(__bf16)b.w;
            *((bf16x8*)x16 + i) = o;
        }
    }
}

// ---------------------------------------------------------------------------
// OT bf16 [772][16384] -> O bf16 [16384][800]; 64x64 tiles, 4-B packed
// accesses both sides. Rows >= 772 and O cols 772..799 read as zero.
// ---------------------------------------------------------------------------
__global__ __launch_bounds__(256) void transposeO64(
    const unsigned short* __restrict__ OT, unsigned short* __restrict__ O)
{
    __shared__ unsigned short tile[64][66];
    const int tid = threadIdx.x;
    const int m0 = blockIdx.x * 64, c0 = blockIdx.y * 64;
    const int half = tid & 31, row8 = tid >> 5;     // 32 col-pairs x 8 rows
    #pragma unroll
    for (int p = 0; p < 8; ++p) {
        const int c = c0 + p * 8 + row8;
        unsigned int v = 0;
        if (c < NSP)
            v = *(const unsigned int*)(OT + (size_t)c * MROWS + m0 + half * 2);
        *(unsigned int*)&tile[p * 8 + row8][half * 2] = v;
    }
    __syncthreads();
    #pragma unroll
    for (int p = 0; p < 8; ++p) {
        const int m = m0 + p * 8 + row8;
        const int c = c0 + half * 2;
        if (c < KP5) {
            unsigned int re = tile[half * 2][p * 8 + row8];
            unsigned int im = tile[half * 2 + 1][p * 8 + row8];
            *(unsigned int*)(O + (size_t)m * KP5 + c) = (im << 16) | re;
        }
    }
}

// ---------------------------------------------------------------------------
// bf16 NT MFMA GEMM: C[M,N] = A[M,K] @ Bt[N,K]^T
// 128x128 tile, BK=32, 4 waves (2x2 of 64x64), 16x16x32 MFMA.
// LDS K-block XOR swizzle on the global-fetch side (2-way = free, m136).
// grid.z batches A/B/C via strideAz/strideBz/strideCz.
// ---------------------------------------------------------------------------
__global__ __launch_bounds__(256) void mfma_nt(
    const __bf16* __restrict__ A, const __bf16* __restrict__ B, void* __restrict__ Cv,
    int M, int N, int K, int lda, int ldb, int ldc,
    long strideAz, long strideBz, long strideCz, int c_bf16,
    const float* __restrict__ addend, const float* __restrict__ gain)
{
    __shared__ __bf16 As[128 * 32];
    __shared__ __bf16 Bs[128 * 32];
    const int tid  = threadIdx.x;
    const int wave = tid >> 6, lane = tid & 63;
    const int lrow = lane & 15, lquad = lane >> 4;
    const int wm = wave >> 1, wn = wave & 1;
    const int m0 = blockIdx.y * 128, n0 = blockIdx.x * 128;
    const __bf16* Az = A + (size_t)blockIdx.z * strideAz;
    const __bf16* Bz = B + (size_t)blockIdx.z * strideBz;

    const int sr = tid >> 2;                               // 0..63
    const int sc = (((tid & 3) ^ ((tid >> 3) & 3))) * 8;   // swizzled K-block
    int ra0 = m0 + sr;      if (ra0 > M - 1) ra0 = M - 1;
    int ra1 = m0 + sr + 64; if (ra1 > M - 1) ra1 = M - 1;
    const int rb0 = n0 + sr, rb1 = n0 + sr + 64;
    __bf16* ldsA0 = As + wave * 512;
    __bf16* ldsA1 = As + 2048 + wave * 512;
    __bf16* ldsB0 = Bs + wave * 512;
    __bf16* ldsB1 = Bs + 2048 + wave * 512;

    const int swz = (lrow >> 1) & 3;                       // reader de-swizzle
    const int fragcol = (lquad ^ swz) * 8;

    f32x4 acc[4][4];
    #pragma unroll
    for (int i = 0; i < 4; ++i)
        #pragma unroll
        for (int j = 0; j < 4; ++j)
            acc[i][j] = (f32x4){0.f, 0.f, 0.f, 0.f};

    for (int k0 = 0; k0 < K; k0 += 32) {
        gl2lds16(Az + (size_t)ra0 * lda + k0 + sc, ldsA0);
        gl2lds16(Az + (size_t)ra1 * lda + k0 + sc, ldsA1);
        gl2lds16(Bz + (size_t)rb0 * ldb + k0 + sc, ldsB0);
        gl2lds16(Bz + (size_t)rb1 * ldb + k0 + sc, ldsB1);
        __syncthreads();
        bf16x8 af[4], bfr[4];
        #pragma unroll
        for (int i = 0; i < 4; ++i) {
            af[i]  = *(const bf16x8*)&As[(wm*64 + i*16 + lrow) * 32 + fragcol];
            bfr[i] = *(const bf16x8*)&Bs[(wn*64 + i*16 + lrow) * 32 + fragcol];
        }
        #pragma unroll
        for (int i = 0; i < 4; ++i)
            #pragma unroll
            for (int j = 0; j < 4; ++j)
                acc[i][j] = __builtin_amdgcn_mfma_f32_16x16x32_bf16(
                    af[i], bfr[j], acc[i][j], 0, 0, 0);
        __syncthreads();
    }

    // C/D layout (verified m89): col = lane&15, row = (lane>>4)*4 + reg
    const int colb = n0 + wn * 64 + lrow;
    const int rowb = m0 + wm * 64 + lquad * 4;
    if (c_bf16) {
        __bf16* C = (__bf16*)Cv + (size_t)blockIdx.z * strideCz;
        #pragma unroll
        for (int i = 0; i < 4; ++i)
            #pragma unroll
            for (int j = 0; j < 4; ++j) {
                const int col = colb + j * 16;
                #pragma unroll
                for (int r = 0; r < 4; ++r) {
                    const int mm = rowb + i * 16 + r;
                    if (mm < M) C[(size_t)mm * ldc + col] = (__bf16)acc[i][j][r];
                }
            }
    } else if (addend) {
        float* C = (float*)Cv;
        const float g = gain[0];
        #pragma unroll
        for (int i = 0; i < 4; ++i)
            #pragma unroll
            for (int j = 0; j < 4; ++j) {
                const int col = colb + j * 16;
                #pragma unroll
                for (int r = 0; r < 4; ++r) {
                    const int mm = rowb + i * 16 + r;
                    if (mm < M) {
                        const size_t off = (size_t)mm * ldc + col;
                        C[off] = addend[off] + g * acc[i][j][r];
                    }
                }
            }
    } else {
        float* C = (float*)Cv + (size_t)blockIdx.z * strideCz;
        #pragma unroll
        for (int i = 0; i < 4; ++i)
            #pragma unroll
            for (int j = 0; j < 4; ++j) {
                const int col = colb + j * 16;
                #pragma unroll
                for (int r = 0; r < 4; ++r) {
                    const int mm = rowb + i * 16 + r;
                    if (mm < M) C[(size_t)mm * ldc + col] = acc[i][j][r];
                }
            }
    }
}

// ---------------------------------------------------------------------------
// Causal complex scan over bf16 spectra (transposed layout), in place over K.
// One block per (b,f) chain; thread t owns 16 consecutive s.
// ---------------------------------------------------------------------------
__global__ __launch_bounds__(256) void scan_blocks(__bf16* __restrict__ spec) {
    const int blk = blockIdx.x;
    const int b = blk / NF, f = blk % NF;
    const int tid = threadIdx.x;
    const int lane = tid & 63, wid = tid >> 6;
    const size_t colbase = (size_t)b * SEQ;
    __bf16* Kre = spec + (size_t)(2*f) * MROWS + colbase;
    __bf16* Kim = Kre + MROWS;
    const __bf16* Vre = Kre + SPECZ;
    const __bf16* Vim = Vre + MROWS;
    const __bf16* Qre = Kre + 2 * SPECZ;
    const __bf16* Qim = Qre + MROWS;
    const int s0 = tid * 16;

    bf16x8 kr0 = *(const bf16x8*)(Kre + s0), kr1 = *(const bf16x8*)(Kre + s0 + 8);
    bf16x8 ki0 = *(const bf16x8*)(Kim + s0), ki1 = *(const bf16x8*)(Kim + s0 + 8);
    bf16x8 vr0 = *(const bf16x8*)(Vre + s0), vr1 = *(const bf16x8*)(Vre + s0 + 8);
    bf16x8 vi0 = *(const bf16x8*)(Vim + s0), vi1 = *(const bf16x8*)(Vim + s0 + 8);

    float pr[16], pi[16];
    #pragma unroll
    for (int u = 0; u < 8; ++u) {
        float a = (float)kr0[u], bq = (float)ki0[u], c = (float)vr0[u], d = (float)vi0[u];
        pr[u] = a * c - bq * d;
        pi[u] = a * d + bq * c;
        float a1 = (float)kr1[u], b1 = (float)ki1[u], c1 = (float)vr1[u], d1 = (float)vi1[u];
        pr[8+u] = a1 * c1 - b1 * d1;
        pi[8+u] = a1 * d1 + b1 * c1;
    }
    #pragma unroll
    for (int j = 1; j < 16; ++j) { pr[j] += pr[j-1]; pi[j] += pi[j-1]; }
    const float totr = pr[15], toti = pi[15];

    float sr = totr, si = toti;
    #pragma unroll
    for (int d = 1; d < 64; d <<= 1) {
        float ur = __shfl_up(sr, d, 64);
        float ui = __shfl_up(si, d, 64);
        if (lane >= d) { sr += ur; si += ui; }
    }
    __shared__ float wsr[4], wsi[4];
    if (lane == 63) { wsr[wid] = sr; wsi[wid] = si; }
    __syncthreads();
    float baser = 0.f, basei = 0.f;
    #pragma unroll
    for (int w = 0; w < 3; ++w)
        if (w < wid) { baser += wsr[w]; basei += wsi[w]; }
    const float exr = baser + sr - totr;
    const float exi = basei + si - toti;

    bf16x8 qr0 = *(const bf16x8*)(Qre + s0), qr1 = *(const bf16x8*)(Qre + s0 + 8);
    bf16x8 qi0 = *(const bf16x8*)(Qim + s0), qi1 = *(const bf16x8*)(Qim + s0 + 8);
    bf16x8 outr0, outr1, outi0, outi1;
    #pragma unroll
    for (int u = 0; u < 8; ++u) {
        float mr = exr + pr[u],   mi = exi + pi[u];
        float qr = (float)qr0[u], qi = (float)qi0[u];
        outr0[u] = (__bf16)(mr * qr + mi * qi);
        outi0[u] = (__bf16)(mi * qr - mr * qi);
        float mr1 = exr + pr[8+u], mi1 = exi + pi[8+u];
        float qr_ = (float)qr1[u], qi_ = (float)qi1[u];
        outr1[u] = (__bf16)(mr1 * qr_ + mi1 * qi_);
        outi1[u] = (__bf16)(mi1 * qr_ - mr1 * qi_);
    }
    *(bf16x8*)(Kre + s0)     = outr0;
    *(bf16x8*)(Kre + s0 + 8) = outr1;
    *(bf16x8*)(Kim + s0)     = outi0;
    *(bf16x8*)(Kim + s0 + 8) = outi1;
}

// ---------------------------------------------------------------------------
// Workspace (bf16): FtabT[772*768] | GT[768*800] | WT[3*768*768]
//  | x16[16384*768] | CTs[2316*768] | spec[3*772*16384]; O overlays specV/Q.
// ---------------------------------------------------------------------------
extern "C" void kernel_launch(void* const* d_in, const int* in_sizes, int n_in,
                              void* d_out, int out_size, void* d_ws, size_t ws_size,
                              hipStream_t stream) {
    const float* x    = (const float*)d_in[0];
    const float* Wk   = (const float*)d_in[1];
    const float* Wv   = (const float*)d_in[2];
    const float* Wq   = (const float*)d_in[3];
    const float* gain = (const float*)d_in[4];
    float* out = (float*)d_out;

    __bf16* FtabT = (__bf16*)d_ws;
    __bf16* GT    = FtabT + (size_t)NSP * D_DIM;
    __bf16* WT    = GT    + (size_t)D_DIM * KP5;
    __bf16* x16   = WT    + (size_t)3 * D_DIM * D_DIM;
    __bf16* CTs   = x16   + (size_t)MROWS * D_DIM;
    __bf16* spec  = CTs   + (size_t)3 * NSP * D_DIM;
    __bf16* O     = spec  + SPECZ;   // over specV/specQ (free after scan)

    // prologue: tables + W transposes + x conversion (one dispatch)
    prologue<<<3264, 256, 0, stream>>>(FtabT, GT, Wk, Wv, Wq, WT, x, x16);

    // stage 2: CTs[z*772+c][e] = FtabT @ WT_z^T  (z-batched, stacked in M)
    mfma_nt<<<dim3(6, 7, 3), 256, 0, stream>>>(
        FtabT, WT, CTs, NSP, D_DIM, D_DIM,
        D_DIM, D_DIM, D_DIM,
        0L, (long)D_DIM * D_DIM, (long)NSP * D_DIM, 1, nullptr, nullptr);

    // stage 3: spec[2316][16384] = CTs @ x16^T  (single dispatch, M-stacked z)
    mfma_nt<<<dim3(128, 19, 1), 256, 0, stream>>>(
        CTs, x16, spec, 3 * NSP, MROWS, D_DIM,
        D_DIM, D_DIM, MROWS, 0L, 0L, 0L, 1, nullptr, nullptr);

    // stage 4: causal binding scan + unbind (in place over specK)
    scan_blocks<<<BATCH * NF, 256, 0, stream>>>(spec);

    // OT -> O bf16 [16384][800] (zero-padded cols)
    transposeO64<<<dim3(MROWS / 64, 13), 256, 0, stream>>>(
        (const unsigned short*)spec, (unsigned short*)O);

    // stage 5: out[16384][768] = x + gain * (O @ GT^T)
    mfma_nt<<<dim3(6, 128, 1), 256, 0, stream>>>(
        O, GT, out, MROWS, D_DIM, KP5,
        KP5, KP5, D_DIM, 0L, 0L, 0L, 0, x, gain);
}